// Round 19
// baseline (210.789 us; speedup 1.0000x reference)
//
#include <hip/hip_runtime.h>
#include <hip/hip_bf16.h>

// GATPredictor: x(8,12,1500) f32 -> 2-layer LSTM(hid64) per (b,n) sequence ->
// 2x GAT(4 heads x 16) over N=1500 graph -> linear head (3) -> (B,3,N) f32.
// 3 dispatches:
//   A) lstm_mask_prep: LSTM (750 blk x 16 seq, merged-phase MFMA) + adjacency
//      bitmask (blocks 750..1031) + fused GAT0 projection.
//   B) gat_mid: flash-MFMA GAT0 aggregation + fused GAT1 projection.
//   C) gat_fin: flash-MFMA GAT1 aggregation + fused linear head -> d_out.
// Round 19: aggs = round-17 variant (best measured). LSTM gates LOG2E-
// prescaled at weight-fragment load (i,f,o x LOG2E; g x 2LOG2E) so every
// sigmoid/tanh uses a bare v_exp (exp2) with no preceding v_mul — removes
// ~192 dependent muls/thread from the serial gate chains. c stays natural;
// tanh(c) keeps its explicit scale.

#define BN 12000
#define NNODE 1500
#define NB 8
#define TT 12
#define NPAD 1536   // padded j extent for esT/edT rows
#define LOG2E 1.44269504f

typedef __bf16 bf16x8 __attribute__((ext_vector_type(8)));
typedef __bf16 bf16x4 __attribute__((ext_vector_type(4)));
typedef float  f32x4  __attribute__((ext_vector_type(4)));

__device__ __forceinline__ float rcpf(float v) { return __builtin_amdgcn_rcpf(v); }
__device__ __forceinline__ float exp2f_(float v) { return __builtin_amdgcn_exp2f(v); }
// prescaled activations: argument already multiplied by LOG2E (sig2) or
// 2*LOG2E (tanh2). tanhc takes natural units.
__device__ __forceinline__ float sig2(float v) { return rcpf(1.f + exp2f_(-v)); }
__device__ __forceinline__ float tanh2(float v) {
    return fmaf(2.f, rcpf(1.f + exp2f_(-v)), -1.f);
}
__device__ __forceinline__ float tanhc(float v) {
    return fmaf(2.f, rcpf(1.f + exp2f_(-2.f * LOG2E * v)), -1.f);
}

// fragment-major hp chunk base (element index): (b,head,jc) -> 512-elem chunk
__device__ __forceinline__ int hp_idx(int b, int head, int jc) {
    return (((b << 2) + head) * 48 + jc) << 9;
}

// load 8 consecutive f32 (global or LDS) -> bf16x8 MFMA fragment
__device__ __forceinline__ bf16x8 ldcvt(const float* p) {
    f32x4 a = *(const f32x4*)p;
    f32x4 b = *(const f32x4*)(p + 4);
    bf16x8 r;
    #pragma unroll
    for (int i = 0; i < 4; ++i) { r[i] = (__bf16)a[i]; r[4 + i] = (__bf16)b[i]; }
    return r;
}

// scaled variant (scale baked before bf16 rounding)
__device__ __forceinline__ bf16x8 ldcvt_s(const float* p, float sc) {
    f32x4 a = *(const f32x4*)p;
    f32x4 b = *(const f32x4*)(p + 4);
    bf16x8 r;
    #pragma unroll
    for (int i = 0; i < 4; ++i) {
        r[i] = (__bf16)(a[i] * sc);
        r[4 + i] = (__bf16)(b[i] * sc);
    }
    return r;
}

// ---------------------------------------------------------------------------
// Kernel A: LSTM (blocks 0..749, 16 seqs) + mask gen (750..1031) + prep0.
// ---------------------------------------------------------------------------
__global__ __launch_bounds__(512, 1) void lstm_mask_prep(
    const float* __restrict__ x,
    const float* __restrict__ Wih0, const float* __restrict__ Whh0,
    const float* __restrict__ bih0, const float* __restrict__ bhh0,
    const float* __restrict__ Wih1, const float* __restrict__ Whh1,
    const float* __restrict__ bih1, const float* __restrict__ bhh1,
    const int* __restrict__ adj, unsigned int* __restrict__ mask,
    const float* __restrict__ gW, const float* __restrict__ asrc,
    const float* __restrict__ adst,
    __bf16* __restrict__ hpT, float* __restrict__ esT, float* __restrict__ edT)
{
    if (blockIdx.x >= 750) {
        int wid  = (blockIdx.x - 750) * 8 + (threadIdx.x >> 6);
        int lane = threadIdx.x & 63;
        #pragma unroll 4
        for (int u = 0; u < 16; ++u) {
            int task = wid * 16 + u;
            int i = task / 24, ch = task - i * 24;
            int j = ch * 64 + lane;
            int a = (i < NNODE && j < NNODE) ? adj[i * NNODE + j] : 0;
            unsigned long long m = __ballot(a > 0);
            if (lane == 0 && i < 1504) *(unsigned long long*)&mask[i * 48 + ch * 2] = m;
        }
        return;
    }

    __shared__ __align__(16) __bf16 h0s[16 * 72];
    __shared__ __align__(16) __bf16 h1s[16 * 72];
    __shared__ __align__(16) float  xls[TT * 16];
    __shared__ float avs[128];
    __shared__ __align__(16) __bf16 hp_t[64 * 24];

    int tid  = threadIdx.x;
    int w    = __builtin_amdgcn_readfirstlane(tid >> 6);
    int lane = tid & 63;
    int l15  = lane & 15;
    int qd   = lane >> 4;
    bool lo  = l15 < 8;
    int dloc = l15 & 7;
    int d    = 8 * w + dloc;

    for (int e = tid; e < (16 * 72) / 2; e += 512) ((unsigned int*)h1s)[e] = 0u;
    if (tid < TT * 16) {
        int t = tid >> 4, m = tid & 15;
        int s = blockIdx.x * 16 + m;
        int bb = s / NNODE, nn = s - bb * NNODE;
        xls[tid] = x[bb * (TT * NNODE) + t * NNODE + nn];
    }
    if (tid < 64)       avs[tid] = asrc[tid] * LOG2E;
    else if (tid < 128) avs[tid] = adst[tid - 64] * LOG2E;

    // gate-column scales: i,f,o -> LOG2E; g -> 2*LOG2E
    int gA = (lo ? 0 : 64) + d;          // i | f
    int gB = (lo ? 128 : 192) + d;       // g | o
    float scA = LOG2E;
    float scB = lo ? 2.f * LOG2E : LOG2E;

    bf16x8 B0A[2], B0B[2], B1A[4], B1B[4];
    #pragma unroll
    for (int kt = 0; kt < 2; ++kt) {
        B0A[kt] = ldcvt_s(&Whh0[gA * 64 + 32 * kt + 8 * qd], scA);
        B0B[kt] = ldcvt_s(&Whh0[gB * 64 + 32 * kt + 8 * qd], scB);
        B1A[kt] = ldcvt_s(&Wih1[gA * 64 + 32 * kt + 8 * qd], scA);
        B1B[kt] = ldcvt_s(&Wih1[gB * 64 + 32 * kt + 8 * qd], scB);
        B1A[kt + 2] = ldcvt_s(&Whh1[gA * 64 + 32 * kt + 8 * qd], scA);
        B1B[kt + 2] = ldcvt_s(&Whh1[gB * 64 + 32 * kt + 8 * qd], scB);
    }
    float b0A = (bih0[gA] + bhh0[gA]) * scA, b0B = (bih0[gB] + bhh0[gB]) * scB;
    float b1A = (bih1[gA] + bhh1[gA]) * scA, b1B = (bih1[gB] + bhh1[gB]) * scB;
    float w0A = Wih0[gA] * scA, w0B = Wih0[gB] * scB;

    float pwi = Wih0[d] * LOG2E,
          pbi = (bih0[d] + bhh0[d]) * LOG2E;
    float pwg = Wih0[128 + d] * (2.f * LOG2E),
          pbg = (bih0[128 + d] + bhh0[128 + d]) * (2.f * LOG2E);
    float pwo = Wih0[192 + d] * LOG2E,
          pbo = (bih0[192 + d] + bhh0[192 + d]) * LOG2E;

    float c0[2], c1[2];
    c0[0] = c0[1] = c1[0] = c1[1] = 0.f;

    __syncthreads();

    #pragma unroll
    for (int rl = 0; rl < 2; ++rl) {
        int rr = lo ? rl : 2 + rl;
        int m = 4 * qd + rr;
        float xv = xls[m];
        float gi = fmaf(pwi, xv, pbi);
        float gg = fmaf(pwg, xv, pbg);
        float go = fmaf(pwo, xv, pbo);
        float c = sig2(gi) * tanh2(gg);
        c0[rl] = c;
        h0s[m * 72 + d] = (__bf16)(sig2(go) * tanhc(c));
    }
    __syncthreads();

    for (int t = 0; t < TT; ++t) {
        bool last = (t == TT - 1);
        bf16x8 a0[2], a1[2];
        #pragma unroll
        for (int kt = 0; kt < 2; ++kt) {
            a0[kt] = *(bf16x8*)&h0s[l15 * 72 + 32 * kt + 8 * qd];
            a1[kt] = *(bf16x8*)&h1s[l15 * 72 + 32 * kt + 8 * qd];
        }
        f32x4 AA1, AB1, AA0, AB0;
        #pragma unroll
        for (int r = 0; r < 4; ++r) { AA1[r] = b1A; AB1[r] = b1B; }
        if (!last) {
            f32x4 xv = *(f32x4*)&xls[(t + 1) * 16 + 4 * qd];
            #pragma unroll
            for (int r = 0; r < 4; ++r) {
                AA0[r] = fmaf(w0A, xv[r], b0A);
                AB0[r] = fmaf(w0B, xv[r], b0B);
            }
        }
        #pragma unroll
        for (int kt = 0; kt < 2; ++kt) {
            AA1 = __builtin_amdgcn_mfma_f32_16x16x32_bf16(a0[kt], B1A[kt], AA1, 0, 0, 0);
            AB1 = __builtin_amdgcn_mfma_f32_16x16x32_bf16(a0[kt], B1B[kt], AB1, 0, 0, 0);
            AA1 = __builtin_amdgcn_mfma_f32_16x16x32_bf16(a1[kt], B1A[kt + 2], AA1, 0, 0, 0);
            AB1 = __builtin_amdgcn_mfma_f32_16x16x32_bf16(a1[kt], B1B[kt + 2], AB1, 0, 0, 0);
        }
        if (!last) {
            #pragma unroll
            for (int kt = 0; kt < 2; ++kt) {
                AA0 = __builtin_amdgcn_mfma_f32_16x16x32_bf16(a0[kt], B0A[kt], AA0, 0, 0, 0);
                AB0 = __builtin_amdgcn_mfma_f32_16x16x32_bf16(a0[kt], B0B[kt], AB0, 0, 0, 0);
            }
        }
        __syncthreads();

        {
            float shA0 = __shfl_xor(lo ? AA1[2] : AA1[0], 8);
            float shA1 = __shfl_xor(lo ? AA1[3] : AA1[1], 8);
            float shB0 = __shfl_xor(lo ? AB1[2] : AB1[0], 8);
            float shB1 = __shfl_xor(lo ? AB1[3] : AB1[1], 8);
            #pragma unroll
            for (int rl = 0; rl < 2; ++rl) {
                int rr = lo ? rl : 2 + rl;
                float ownA = AA1[rr], ownB = AB1[rr];
                float shA = rl ? shA1 : shA0, shB = rl ? shB1 : shB0;
                float gi = lo ? ownA : shA;      // scaled LOG2E
                float gf = lo ? shA : ownA;      // scaled LOG2E
                float gg = lo ? ownB : shB;      // scaled 2*LOG2E
                float go = lo ? shB : ownB;      // scaled LOG2E
                float c = sig2(gf) * c1[rl] + sig2(gi) * tanh2(gg);
                c1[rl] = c;
                float hv = sig2(go) * tanhc(c);
                int m = 4 * qd + rr;
                h1s[m * 72 + d] = (__bf16)hv;
            }
        }
        if (!last) {
            float shA0 = __shfl_xor(lo ? AA0[2] : AA0[0], 8);
            float shA1 = __shfl_xor(lo ? AA0[3] : AA0[1], 8);
            float shB0 = __shfl_xor(lo ? AB0[2] : AB0[0], 8);
            float shB1 = __shfl_xor(lo ? AB0[3] : AB0[1], 8);
            #pragma unroll
            for (int rl = 0; rl < 2; ++rl) {
                int rr = lo ? rl : 2 + rl;
                float ownA = AA0[rr], ownB = AB0[rr];
                float shA = rl ? shA1 : shA0, shB = rl ? shB1 : shB0;
                float gi = lo ? ownA : shA;
                float gf = lo ? shA : ownA;
                float gg = lo ? ownB : shB;
                float go = lo ? shB : ownB;
                float c = sig2(gf) * c0[rl] + sig2(gi) * tanh2(gg);
                c0[rl] = c;
                int m = 4 * qd + rr;
                h0s[m * 72 + d] = (__bf16)(sig2(go) * tanhc(c));
            }
        }
        __syncthreads();
    }

    // fused prep0
    int s0 = blockIdx.x * 16;
    if (w < 4) {
        int mt = w;
        bf16x8 Bf0 = *(bf16x8*)&h1s[l15 * 72 + 8 * qd];
        bf16x8 Bf1 = *(bf16x8*)&h1s[l15 * 72 + 32 + 8 * qd];
        bf16x8 A0 = ldcvt(&gW[(mt * 16 + l15) * 64 + 8 * qd]);
        bf16x8 A1 = ldcvt(&gW[(mt * 16 + l15) * 64 + 32 + 8 * qd]);
        f32x4 a = {0.f, 0.f, 0.f, 0.f};
        a = __builtin_amdgcn_mfma_f32_16x16x32_bf16(A0, Bf0, a, 0, 0, 0);
        a = __builtin_amdgcn_mfma_f32_16x16x32_bf16(A1, Bf1, a, 0, 0, 0);
        float ts = 0.f, td = 0.f;
        #pragma unroll
        for (int r = 0; r < 4; ++r) {
            int dd = mt * 16 + qd * 4 + r;
            ts = fmaf(a[r], avs[dd], ts);
            td = fmaf(a[r], avs[64 + dd], td);
            hp_t[dd * 24 + l15] = (__bf16)a[r];
        }
        ts += __shfl_xor(ts, 16); ts += __shfl_xor(ts, 32);
        td += __shfl_xor(td, 16); td += __shfl_xor(td, 32);
        if (qd == 0) {
            int s = s0 + l15, b = s / NNODE, n = s - b * NNODE;
            esT[(b * 4 + mt) * NPAD + n] = ts;
            edT[(b * 4 + mt) * NPAD + n] = td;
        }
    }
    __syncthreads();
    if (tid < 256) {
        int dim = tid >> 2, seg = tid & 3;
        int head = dim >> 4, dl = dim & 15;
        int b0 = s0 / NNODE, b1e = (s0 + 15) / NNODE;
        if (b0 == b1e) {
            // n0 is a multiple of 4 (NOT 16). Per-4-node-group chunk coords:
            // a 4-aligned group never crosses the 32-j chunk boundary.
            int n0 = s0 - b0 * NNODE;
            int nj = n0 + seg * 4;
            int jc = nj >> 5, ko = nj & 31;
            bf16x4 v = *(bf16x4*)&hp_t[dim * 24 + seg * 4];
            *(bf16x4*)&hpT[hp_idx(b0, head, jc) + dl * 32 + ko] = v;
        } else {
            #pragma unroll
            for (int u = 0; u < 4; ++u) {
                int ss = s0 + seg * 4 + u;
                int b = ss / NNODE, n = ss - b * NNODE;
                hpT[hp_idx(b, head, n >> 5) + dl * 32 + (n & 31)] =
                    hp_t[dim * 24 + seg * 4 + u];
            }
        }
    }
}

// ---------------------------------------------------------------------------
// Kernel B: GAT0 aggregation + fused GAT1 projection.
// Block = 16 nodes x 8 waves = (head hh) x (j-half jh, 24 chunks each).
// Round-17 structure (best measured): pipelined loads, VALU S + shuffles.
// ---------------------------------------------------------------------------
__global__ __launch_bounds__(512, 1) void gat_mid(
    const __bf16* __restrict__ hpT, const float* __restrict__ esT,
    const float* __restrict__ edT, const unsigned int* __restrict__ mask,
    const float* __restrict__ gW, const float* __restrict__ asrc,
    const float* __restrict__ adst,
    __bf16* __restrict__ hpT1, float* __restrict__ esT1, float* __restrict__ edT1)
{
    __shared__ __align__(16) float edls[4 * NPAD];   // 24 KB
    __shared__ unsigned int mskls[48 * 16];          // 3 KB [chunk][i]
    __shared__ float Ss[8][16];
    __shared__ __align__(16) f32x4 accs[256];        // 4 KB (jh=1 partials)
    __shared__ float hbuf[16 * 72];                  // 4.5 KB [node][dim]
    __shared__ float avs[128];
    __shared__ __align__(16) __bf16 hp1_t[64 * 24];  // 3 KB [dim][node]

    int tid  = threadIdx.x;
    int wv   = tid >> 6;
    int lane = tid & 63;
    int l15  = lane & 15;
    int qd   = lane >> 4;
    int hh   = wv & 3;          // head
    int jh   = wv >> 2;         // j-half
    int b    = blockIdx.x / 94;
    int i0   = (blockIdx.x % 94) * 16;

    if (tid < 64)       avs[tid] = asrc[tid] * LOG2E;
    else if (tid < 128) avs[tid] = adst[tid - 64] * LOG2E;
    {
        const float4* src = (const float4*)(edT + (b * 4) * NPAD);
        float4* dst = (float4*)edls;
        for (int u = tid; u < NPAD; u += 512) dst[u] = src[u];
    }
    for (int u = tid; u < 16 * 48; u += 512) {
        int il = u / 48, c = u - il * 48;
        mskls[c * 16 + il] = mask[(i0 + il) * 48 + c];
    }
    __syncthreads();

    const __bf16* Bbase = hpT + hp_idx(b, hh, 0) + l15 * 32 + qd * 8;
    const float* edrow = edls + hh * NPAD;
    float esv = esT[(b * 4 + hh) * NPAD + i0 + l15];

    f32x4 acc = {0.f, 0.f, 0.f, 0.f};
    float S = 0.f;

    int base = jh * 24;
    int qsh = qd * 8;
    bf16x8 Bp0 = *(const bf16x8*)(Bbase + ((base + 0) << 9));
    bf16x8 Bp1 = *(const bf16x8*)(Bbase + ((base + 1) << 9));
    float4 e0p = *(const float4*)&edrow[(base + 0) * 32 + qsh];
    float4 e1p = *(const float4*)&edrow[(base + 0) * 32 + qsh + 4];
    unsigned int mp = mskls[(base + 0) * 16 + l15];

    #pragma unroll 2
    for (int u = 0; u < 24; ++u) {
        int jn1 = base + (u + 1 < 24 ? u + 1 : 23);
        int jn2 = base + (u + 2 < 24 ? u + 2 : 23);
        float4 e0n = *(const float4*)&edrow[jn1 * 32 + qsh];
        float4 e1n = *(const float4*)&edrow[jn1 * 32 + qsh + 4];
        unsigned int mn = mskls[jn1 * 16 + l15];
        bf16x8 Bn = *(const bf16x8*)(Bbase + (jn2 << 9));

        unsigned int mb = (mp >> qsh) & 0xffu;
        float ej[8] = {e0p.x, e0p.y, e0p.z, e0p.w, e1p.x, e1p.y, e1p.z, e1p.w};
        bf16x8 A;
        #pragma unroll
        for (int jj = 0; jj < 8; ++jj) {
            float e = esv + ej[jj];
            e = fmaxf(e, 0.2f * e);
            float p = ((mb >> jj) & 1u) ? exp2f_(e) : 0.f;
            S += p;
            A[jj] = (__bf16)p;
        }
        acc = __builtin_amdgcn_mfma_f32_16x16x32_bf16(A, Bp0, acc, 0, 0, 0);

        Bp0 = Bp1; Bp1 = Bn; e0p = e0n; e1p = e1n; mp = mn;
    }

    S += __shfl_xor(S, 16);
    S += __shfl_xor(S, 32);
    if (qd == 0) Ss[wv][l15] = S;
    if (jh == 1) accs[hh * 64 + lane] = acc;
    __syncthreads();

    if (jh == 0) {
        f32x4 o = accs[hh * 64 + lane];
        #pragma unroll
        for (int r = 0; r < 4; ++r) {
            float st = Ss[hh][qd * 4 + r] + Ss[4 + hh][qd * 4 + r];
            float rs = rcpf(st);
            hbuf[(qd * 4 + r) * 72 + (hh << 4) + l15] =
                fmaxf((acc[r] + o[r]) * rs, 0.f);
        }
    }
    __syncthreads();

    // fused prep1: waves 0..3 (jh==0), mt = hh
    if (jh == 0) {
        int mt = hh;
        bf16x8 Bf0 = ldcvt(&hbuf[l15 * 72 + 8 * qd]);
        bf16x8 Bf1 = ldcvt(&hbuf[l15 * 72 + 32 + 8 * qd]);
        bf16x8 A0 = ldcvt(&gW[(mt * 16 + l15) * 64 + 8 * qd]);
        bf16x8 A1 = ldcvt(&gW[(mt * 16 + l15) * 64 + 32 + 8 * qd]);
        f32x4 a = {0.f, 0.f, 0.f, 0.f};
        a = __builtin_amdgcn_mfma_f32_16x16x32_bf16(A0, Bf0, a, 0, 0, 0);
        a = __builtin_amdgcn_mfma_f32_16x16x32_bf16(A1, Bf1, a, 0, 0, 0);
        float ts = 0.f, td = 0.f;
        #pragma unroll
        for (int r = 0; r < 4; ++r) {
            int dd = mt * 16 + qd * 4 + r;
            ts = fmaf(a[r], avs[dd], ts);
            td = fmaf(a[r], avs[64 + dd], td);
            hp1_t[dd * 24 + l15] = (__bf16)a[r];
        }
        ts += __shfl_xor(ts, 16); ts += __shfl_xor(ts, 32);
        td += __shfl_xor(td, 16); td += __shfl_xor(td, 32);
        if (qd == 0) {
            int n = i0 + l15;
            esT1[(b * 4 + mt) * NPAD + n] = ts;
            edT1[(b * 4 + mt) * NPAD + n] = td;
        }
    }
    __syncthreads();
    if (tid < 256) {
        int dim = tid >> 2, seg = tid & 3;
        int head = dim >> 4, dl = dim & 15;
        int nn0 = i0 + seg * 4;          // i0 multiple of 16 -> same chunk
        int jc = nn0 >> 5, ko = nn0 & 31;
        bf16x4 v = *(bf16x4*)&hp1_t[dim * 24 + seg * 4];
        *(bf16x4*)&hpT1[hp_idx(b, head, jc) + dl * 32 + ko] = v;
    }
}

// ---------------------------------------------------------------------------
// Kernel C: GAT1 aggregation + fused linear head -> d_out.
// Round-17 structure.
// ---------------------------------------------------------------------------
__global__ __launch_bounds__(512, 1) void gat_fin(
    const __bf16* __restrict__ hpT, const float* __restrict__ esT,
    const float* __restrict__ edT, const unsigned int* __restrict__ mask,
    const float* __restrict__ oW, const float* __restrict__ ob,
    float* __restrict__ outp)
{
    __shared__ __align__(16) float edls[4 * NPAD];   // 24 KB
    __shared__ unsigned int mskls[48 * 16];          // 3 KB
    __shared__ float Ss[8][16];
    __shared__ __align__(16) f32x4 accs[256];        // 4 KB
    __shared__ float hbuf[16 * 72];
    __shared__ float oWs[192];
    __shared__ float obs[3];

    int tid  = threadIdx.x;
    int wv   = tid >> 6;
    int lane = tid & 63;
    int l15  = lane & 15;
    int qd   = lane >> 4;
    int hh   = wv & 3;
    int jh   = wv >> 2;
    int b    = blockIdx.x / 94;
    int i0   = (blockIdx.x % 94) * 16;

    if (tid < 192) oWs[tid] = oW[tid];
    if (tid < 3)   obs[tid] = ob[tid];
    {
        const float4* src = (const float4*)(edT + (b * 4) * NPAD);
        float4* dst = (float4*)edls;
        for (int u = tid; u < NPAD; u += 512) dst[u] = src[u];
    }
    for (int u = tid; u < 16 * 48; u += 512) {
        int il = u / 48, c = u - il * 48;
        mskls[c * 16 + il] = mask[(i0 + il) * 48 + c];
    }
    __syncthreads();

    const __bf16* Bbase = hpT + hp_idx(b, hh, 0) + l15 * 32 + qd * 8;
    const float* edrow = edls + hh * NPAD;
    float esv = esT[(b * 4 + hh) * NPAD + i0 + l15];

    f32x4 acc = {0.f, 0.f, 0.f, 0.f};
    float S = 0.f;

    int base = jh * 24;
    int qsh = qd * 8;
    bf16x8 Bp0 = *(const bf16x8*)(Bbase + ((base + 0) << 9));
    bf16x8 Bp1 = *(const bf16x8*)(Bbase + ((base + 1) << 9));
    float4 e0p = *(const float4*)&edrow[(base + 0) * 32 + qsh];
    float4 e1p = *(const float4*)&edrow[(base + 0) * 32 + qsh + 4];
    unsigned int mp = mskls[(base + 0) * 16 + l15];

    #pragma unroll 2
    for (int u = 0; u < 24; ++u) {
        int jn1 = base + (u + 1 < 24 ? u + 1 : 23);
        int jn2 = base + (u + 2 < 24 ? u + 2 : 23);
        float4 e0n = *(const float4*)&edrow[jn1 * 32 + qsh];
        float4 e1n = *(const float4*)&edrow[jn1 * 32 + qsh + 4];
        unsigned int mn = mskls[jn1 * 16 + l15];
        bf16x8 Bn = *(const bf16x8*)(Bbase + (jn2 << 9));

        unsigned int mb = (mp >> qsh) & 0xffu;
        float ej[8] = {e0p.x, e0p.y, e0p.z, e0p.w, e1p.x, e1p.y, e1p.z, e1p.w};
        bf16x8 A;
        #pragma unroll
        for (int jj = 0; jj < 8; ++jj) {
            float e = esv + ej[jj];
            e = fmaxf(e, 0.2f * e);
            float p = ((mb >> jj) & 1u) ? exp2f_(e) : 0.f;
            S += p;
            A[jj] = (__bf16)p;
        }
        acc = __builtin_amdgcn_mfma_f32_16x16x32_bf16(A, Bp0, acc, 0, 0, 0);

        Bp0 = Bp1; Bp1 = Bn; e0p = e0n; e1p = e1n; mp = mn;
    }

    S += __shfl_xor(S, 16);
    S += __shfl_xor(S, 32);
    if (qd == 0) Ss[wv][l15] = S;
    if (jh == 1) accs[hh * 64 + lane] = acc;
    __syncthreads();

    if (jh == 0) {
        f32x4 o = accs[hh * 64 + lane];
        #pragma unroll
        for (int r = 0; r < 4; ++r) {
            float st = Ss[hh][qd * 4 + r] + Ss[4 + hh][qd * 4 + r];
            float rs = rcpf(st);
            hbuf[(qd * 4 + r) * 72 + (hh << 4) + l15] =
                fmaxf((acc[r] + o[r]) * rs, 0.f);
        }
    }
    __syncthreads();

    if (tid < 192) {
        int idx = tid >> 2, ks = tid & 3;
        int nl = idx & 15, o = idx >> 4;
        if (i0 + nl < NNODE) {
            const float* hb = &hbuf[nl * 72 + ks * 16];
            float a = 0.f;
            #pragma unroll
            for (int kk = 0; kk < 16; ++kk)
                a = fmaf(hb[kk], oWs[o * 64 + ks * 16 + kk], a);
            a += __shfl_xor(a, 1);
            a += __shfl_xor(a, 2);
            if (ks == 0)
                outp[(long)b * 3 * NNODE + o * NNODE + i0 + nl] = a + obs[o];
        }
    }
}

// ---------------------------------------------------------------------------
extern "C" void kernel_launch(void* const* d_in, const int* in_sizes, int n_in,
                              void* d_out, int out_size, void* d_ws, size_t ws_size,
                              hipStream_t stream) {
    const float* x    = (const float*)d_in[0];
    const int*   adj  = (const int*)d_in[1];
    const float* Wih0 = (const float*)d_in[2];
    const float* Whh0 = (const float*)d_in[3];
    const float* bih0 = (const float*)d_in[4];
    const float* bhh0 = (const float*)d_in[5];
    const float* Wih1 = (const float*)d_in[6];
    const float* Whh1 = (const float*)d_in[7];
    const float* bih1 = (const float*)d_in[8];
    const float* bhh1 = (const float*)d_in[9];
    const float* g0W  = (const float*)d_in[10];
    const float* g0s  = (const float*)d_in[11];
    const float* g0d  = (const float*)d_in[12];
    const float* g1W  = (const float*)d_in[13];
    const float* g1s  = (const float*)d_in[14];
    const float* g1d  = (const float*)d_in[15];
    const float* oW   = (const float*)d_in[16];
    const float* ob   = (const float*)d_in[17];

    float* ws = (float*)d_ws;
    float*        esT0  = ws;                              // 49152
    float*        edT0  = ws + 49152;                      // 49152
    float*        esT1  = ws + 98304;                      // 49152
    float*        edT1  = ws + 147456;                     // 49152
    __bf16*       hpT0  = (__bf16*)(ws + 196608);          // 786432 bf16
    __bf16*       hpT1  = (__bf16*)(ws + 589824);          // 786432 bf16
    unsigned int* maskp = (unsigned int*)(ws + 983040);    // 72192 u32

    lstm_mask_prep<<<1032, 512, 0, stream>>>(x, Wih0, Whh0, bih0, bhh0,
                                             Wih1, Whh1, bih1, bhh1,
                                             adj, maskp, g0W, g0s, g0d,
                                             hpT0, esT0, edT0);
    gat_mid<<<752, 512, 0, stream>>>(hpT0, esT0, edT0, maskp,
                                     g1W, g1s, g1d, hpT1, esT1, edT1);
    gat_fin<<<752, 512, 0, stream>>>(hpT1, esT1, edT1, maskp,
                                     oW, ob, (float*)d_out);
}

// Round 20
// 187.611 us; speedup vs baseline: 1.1235x; 1.1235x over previous
//
#include <hip/hip_runtime.h>
#include <hip/hip_bf16.h>

// GATPredictor: x(8,12,1500) f32 -> 2-layer LSTM(hid64) per (b,n) sequence ->
// 2x GAT(4 heads x 16) over N=1500 graph -> linear head (3) -> (B,3,N) f32.
// FINAL (round-17 configuration — best measured, 187.9 us):
//   A) lstm_mask_prep: LSTM (750 blk x 16 seq, merged-phase MFMA) + adjacency
//      bitmask (blocks 750..1031) + fused GAT0 projection.
//   B) gat_mid: flash-MFMA GAT0 aggregation + fused GAT1 projection.
//   C) gat_fin: flash-MFMA GAT1 aggregation + fused linear head -> d_out.
// NOTE (r19 lesson): kernel A sits exactly at the 64-VGPR occupancy boundary
// (VGPR=60). Any change adding live scalars (e.g. prescaled gate constants)
// pushes it to 72 VGPR -> occupancy 34%->19% -> +22 us. Don't.

#define BN 12000
#define NNODE 1500
#define NB 8
#define TT 12
#define NPAD 1536   // padded j extent for esT/edT rows
#define LOG2E 1.44269504f

typedef __bf16 bf16x8 __attribute__((ext_vector_type(8)));
typedef __bf16 bf16x4 __attribute__((ext_vector_type(4)));
typedef float  f32x4  __attribute__((ext_vector_type(4)));

__device__ __forceinline__ float rcpf(float v) { return __builtin_amdgcn_rcpf(v); }
__device__ __forceinline__ float exp2f_(float v) { return __builtin_amdgcn_exp2f(v); }
__device__ __forceinline__ float sigf(float v) { return rcpf(1.f + __expf(-v)); }
__device__ __forceinline__ float tanhf_(float v) {
    return fmaf(2.f, rcpf(1.f + __expf(-2.f * v)), -1.f);
}

// fragment-major hp chunk base (element index): (b,head,jc) -> 512-elem chunk
__device__ __forceinline__ int hp_idx(int b, int head, int jc) {
    return (((b << 2) + head) * 48 + jc) << 9;
}

// load 8 consecutive f32 (global or LDS) -> bf16x8 MFMA fragment
__device__ __forceinline__ bf16x8 ldcvt(const float* p) {
    f32x4 a = *(const f32x4*)p;
    f32x4 b = *(const f32x4*)(p + 4);
    bf16x8 r;
    #pragma unroll
    for (int i = 0; i < 4; ++i) { r[i] = (__bf16)a[i]; r[4 + i] = (__bf16)b[i]; }
    return r;
}

// ---------------------------------------------------------------------------
// Kernel A: LSTM (blocks 0..749, 16 seqs) + mask gen (750..1031) + prep0.
// ---------------------------------------------------------------------------
__global__ __launch_bounds__(512, 1) void lstm_mask_prep(
    const float* __restrict__ x,
    const float* __restrict__ Wih0, const float* __restrict__ Whh0,
    const float* __restrict__ bih0, const float* __restrict__ bhh0,
    const float* __restrict__ Wih1, const float* __restrict__ Whh1,
    const float* __restrict__ bih1, const float* __restrict__ bhh1,
    const int* __restrict__ adj, unsigned int* __restrict__ mask,
    const float* __restrict__ gW, const float* __restrict__ asrc,
    const float* __restrict__ adst,
    __bf16* __restrict__ hpT, float* __restrict__ esT, float* __restrict__ edT)
{
    if (blockIdx.x >= 750) {
        int wid  = (blockIdx.x - 750) * 8 + (threadIdx.x >> 6);
        int lane = threadIdx.x & 63;
        #pragma unroll 4
        for (int u = 0; u < 16; ++u) {
            int task = wid * 16 + u;
            int i = task / 24, ch = task - i * 24;
            int j = ch * 64 + lane;
            int a = (i < NNODE && j < NNODE) ? adj[i * NNODE + j] : 0;
            unsigned long long m = __ballot(a > 0);
            if (lane == 0 && i < 1504) *(unsigned long long*)&mask[i * 48 + ch * 2] = m;
        }
        return;
    }

    __shared__ __align__(16) __bf16 h0s[16 * 72];
    __shared__ __align__(16) __bf16 h1s[16 * 72];
    __shared__ __align__(16) float  xls[TT * 16];
    __shared__ float avs[128];
    __shared__ __align__(16) __bf16 hp_t[64 * 24];

    int tid  = threadIdx.x;
    int w    = __builtin_amdgcn_readfirstlane(tid >> 6);
    int lane = tid & 63;
    int l15  = lane & 15;
    int qd   = lane >> 4;
    bool lo  = l15 < 8;
    int dloc = l15 & 7;
    int d    = 8 * w + dloc;

    for (int e = tid; e < (16 * 72) / 2; e += 512) ((unsigned int*)h1s)[e] = 0u;
    if (tid < TT * 16) {
        int t = tid >> 4, m = tid & 15;
        int s = blockIdx.x * 16 + m;
        int bb = s / NNODE, nn = s - bb * NNODE;
        xls[tid] = x[bb * (TT * NNODE) + t * NNODE + nn];
    }
    if (tid < 64)       avs[tid] = asrc[tid] * LOG2E;
    else if (tid < 128) avs[tid] = adst[tid - 64] * LOG2E;

    int gA = (lo ? 0 : 64) + d;
    int gB = (lo ? 128 : 192) + d;
    bf16x8 B0A[2], B0B[2], B1A[4], B1B[4];
    #pragma unroll
    for (int kt = 0; kt < 2; ++kt) {
        B0A[kt] = ldcvt(&Whh0[gA * 64 + 32 * kt + 8 * qd]);
        B0B[kt] = ldcvt(&Whh0[gB * 64 + 32 * kt + 8 * qd]);
        B1A[kt] = ldcvt(&Wih1[gA * 64 + 32 * kt + 8 * qd]);
        B1B[kt] = ldcvt(&Wih1[gB * 64 + 32 * kt + 8 * qd]);
        B1A[kt + 2] = ldcvt(&Whh1[gA * 64 + 32 * kt + 8 * qd]);
        B1B[kt + 2] = ldcvt(&Whh1[gB * 64 + 32 * kt + 8 * qd]);
    }
    float b0A = bih0[gA] + bhh0[gA], b0B = bih0[gB] + bhh0[gB];
    float b1A = bih1[gA] + bhh1[gA], b1B = bih1[gB] + bhh1[gB];
    float w0A = Wih0[gA], w0B = Wih0[gB];

    float pwi = Wih0[d],       pbi = bih0[d]       + bhh0[d];
    float pwg = Wih0[128 + d], pbg = bih0[128 + d] + bhh0[128 + d];
    float pwo = Wih0[192 + d], pbo = bih0[192 + d] + bhh0[192 + d];

    float c0[2], c1[2];
    c0[0] = c0[1] = c1[0] = c1[1] = 0.f;

    __syncthreads();

    #pragma unroll
    for (int rl = 0; rl < 2; ++rl) {
        int rr = lo ? rl : 2 + rl;
        int m = 4 * qd + rr;
        float xv = xls[m];
        float gi = fmaf(pwi, xv, pbi);
        float gg = fmaf(pwg, xv, pbg);
        float go = fmaf(pwo, xv, pbo);
        float c = sigf(gi) * tanhf_(gg);
        c0[rl] = c;
        h0s[m * 72 + d] = (__bf16)(sigf(go) * tanhf_(c));
    }
    __syncthreads();

    for (int t = 0; t < TT; ++t) {
        bool last = (t == TT - 1);
        bf16x8 a0[2], a1[2];
        #pragma unroll
        for (int kt = 0; kt < 2; ++kt) {
            a0[kt] = *(bf16x8*)&h0s[l15 * 72 + 32 * kt + 8 * qd];
            a1[kt] = *(bf16x8*)&h1s[l15 * 72 + 32 * kt + 8 * qd];
        }
        f32x4 AA1, AB1, AA0, AB0;
        #pragma unroll
        for (int r = 0; r < 4; ++r) { AA1[r] = b1A; AB1[r] = b1B; }
        if (!last) {
            f32x4 xv = *(f32x4*)&xls[(t + 1) * 16 + 4 * qd];
            #pragma unroll
            for (int r = 0; r < 4; ++r) {
                AA0[r] = fmaf(w0A, xv[r], b0A);
                AB0[r] = fmaf(w0B, xv[r], b0B);
            }
        }
        #pragma unroll
        for (int kt = 0; kt < 2; ++kt) {
            AA1 = __builtin_amdgcn_mfma_f32_16x16x32_bf16(a0[kt], B1A[kt], AA1, 0, 0, 0);
            AB1 = __builtin_amdgcn_mfma_f32_16x16x32_bf16(a0[kt], B1B[kt], AB1, 0, 0, 0);
            AA1 = __builtin_amdgcn_mfma_f32_16x16x32_bf16(a1[kt], B1A[kt + 2], AA1, 0, 0, 0);
            AB1 = __builtin_amdgcn_mfma_f32_16x16x32_bf16(a1[kt], B1B[kt + 2], AB1, 0, 0, 0);
        }
        if (!last) {
            #pragma unroll
            for (int kt = 0; kt < 2; ++kt) {
                AA0 = __builtin_amdgcn_mfma_f32_16x16x32_bf16(a0[kt], B0A[kt], AA0, 0, 0, 0);
                AB0 = __builtin_amdgcn_mfma_f32_16x16x32_bf16(a0[kt], B0B[kt], AB0, 0, 0, 0);
            }
        }
        __syncthreads();

        {
            float shA0 = __shfl_xor(lo ? AA1[2] : AA1[0], 8);
            float shA1 = __shfl_xor(lo ? AA1[3] : AA1[1], 8);
            float shB0 = __shfl_xor(lo ? AB1[2] : AB1[0], 8);
            float shB1 = __shfl_xor(lo ? AB1[3] : AB1[1], 8);
            #pragma unroll
            for (int rl = 0; rl < 2; ++rl) {
                int rr = lo ? rl : 2 + rl;
                float ownA = AA1[rr], ownB = AB1[rr];
                float shA = rl ? shA1 : shA0, shB = rl ? shB1 : shB0;
                float gi = lo ? ownA : shA;
                float gf = lo ? shA : ownA;
                float gg = lo ? ownB : shB;
                float go = lo ? shB : ownB;
                float c = sigf(gf) * c1[rl] + sigf(gi) * tanhf_(gg);
                c1[rl] = c;
                float hv = sigf(go) * tanhf_(c);
                int m = 4 * qd + rr;
                h1s[m * 72 + d] = (__bf16)hv;
            }
        }
        if (!last) {
            float shA0 = __shfl_xor(lo ? AA0[2] : AA0[0], 8);
            float shA1 = __shfl_xor(lo ? AA0[3] : AA0[1], 8);
            float shB0 = __shfl_xor(lo ? AB0[2] : AB0[0], 8);
            float shB1 = __shfl_xor(lo ? AB0[3] : AB0[1], 8);
            #pragma unroll
            for (int rl = 0; rl < 2; ++rl) {
                int rr = lo ? rl : 2 + rl;
                float ownA = AA0[rr], ownB = AB0[rr];
                float shA = rl ? shA1 : shA0, shB = rl ? shB1 : shB0;
                float gi = lo ? ownA : shA;
                float gf = lo ? shA : ownA;
                float gg = lo ? ownB : shB;
                float go = lo ? shB : ownB;
                float c = sigf(gf) * c0[rl] + sigf(gi) * tanhf_(gg);
                c0[rl] = c;
                int m = 4 * qd + rr;
                h0s[m * 72 + d] = (__bf16)(sigf(go) * tanhf_(c));
            }
        }
        __syncthreads();
    }

    // fused prep0
    int s0 = blockIdx.x * 16;
    if (w < 4) {
        int mt = w;
        bf16x8 Bf0 = *(bf16x8*)&h1s[l15 * 72 + 8 * qd];
        bf16x8 Bf1 = *(bf16x8*)&h1s[l15 * 72 + 32 + 8 * qd];
        bf16x8 A0 = ldcvt(&gW[(mt * 16 + l15) * 64 + 8 * qd]);
        bf16x8 A1 = ldcvt(&gW[(mt * 16 + l15) * 64 + 32 + 8 * qd]);
        f32x4 a = {0.f, 0.f, 0.f, 0.f};
        a = __builtin_amdgcn_mfma_f32_16x16x32_bf16(A0, Bf0, a, 0, 0, 0);
        a = __builtin_amdgcn_mfma_f32_16x16x32_bf16(A1, Bf1, a, 0, 0, 0);
        float ts = 0.f, td = 0.f;
        #pragma unroll
        for (int r = 0; r < 4; ++r) {
            int dd = mt * 16 + qd * 4 + r;
            ts = fmaf(a[r], avs[dd], ts);
            td = fmaf(a[r], avs[64 + dd], td);
            hp_t[dd * 24 + l15] = (__bf16)a[r];
        }
        ts += __shfl_xor(ts, 16); ts += __shfl_xor(ts, 32);
        td += __shfl_xor(td, 16); td += __shfl_xor(td, 32);
        if (qd == 0) {
            int s = s0 + l15, b = s / NNODE, n = s - b * NNODE;
            esT[(b * 4 + mt) * NPAD + n] = ts;
            edT[(b * 4 + mt) * NPAD + n] = td;
        }
    }
    __syncthreads();
    if (tid < 256) {
        int dim = tid >> 2, seg = tid & 3;
        int head = dim >> 4, dl = dim & 15;
        int b0 = s0 / NNODE, b1e = (s0 + 15) / NNODE;
        if (b0 == b1e) {
            // n0 is a multiple of 4 (NOT 16). Per-4-node-group chunk coords:
            // a 4-aligned group never crosses the 32-j chunk boundary.
            int n0 = s0 - b0 * NNODE;
            int nj = n0 + seg * 4;
            int jc = nj >> 5, ko = nj & 31;
            bf16x4 v = *(bf16x4*)&hp_t[dim * 24 + seg * 4];
            *(bf16x4*)&hpT[hp_idx(b0, head, jc) + dl * 32 + ko] = v;
        } else {
            #pragma unroll
            for (int u = 0; u < 4; ++u) {
                int ss = s0 + seg * 4 + u;
                int b = ss / NNODE, n = ss - b * NNODE;
                hpT[hp_idx(b, head, n >> 5) + dl * 32 + (n & 31)] =
                    hp_t[dim * 24 + seg * 4 + u];
            }
        }
    }
}

// ---------------------------------------------------------------------------
// Kernel B: GAT0 aggregation + fused GAT1 projection.
// Block = 16 nodes x 8 waves = (head hh) x (j-half jh, 24 chunks each).
// Inner loop software-pipelined: B prefetch depth 2, ed/mask depth 1.
// ---------------------------------------------------------------------------
__global__ __launch_bounds__(512, 1) void gat_mid(
    const __bf16* __restrict__ hpT, const float* __restrict__ esT,
    const float* __restrict__ edT, const unsigned int* __restrict__ mask,
    const float* __restrict__ gW, const float* __restrict__ asrc,
    const float* __restrict__ adst,
    __bf16* __restrict__ hpT1, float* __restrict__ esT1, float* __restrict__ edT1)
{
    __shared__ __align__(16) float edls[4 * NPAD];   // 24 KB
    __shared__ unsigned int mskls[48 * 16];          // 3 KB [chunk][i]
    __shared__ float Ss[8][16];
    __shared__ __align__(16) f32x4 accs[256];        // 4 KB (jh=1 partials)
    __shared__ float hbuf[16 * 72];                  // 4.5 KB [node][dim]
    __shared__ float avs[128];
    __shared__ __align__(16) __bf16 hp1_t[64 * 24];  // 3 KB [dim][node]

    int tid  = threadIdx.x;
    int wv   = tid >> 6;
    int lane = tid & 63;
    int l15  = lane & 15;
    int qd   = lane >> 4;
    int hh   = wv & 3;          // head
    int jh   = wv >> 2;         // j-half
    int b    = blockIdx.x / 94;
    int i0   = (blockIdx.x % 94) * 16;

    if (tid < 64)       avs[tid] = asrc[tid] * LOG2E;
    else if (tid < 128) avs[tid] = adst[tid - 64] * LOG2E;
    {
        const float4* src = (const float4*)(edT + (b * 4) * NPAD);
        float4* dst = (float4*)edls;
        for (int u = tid; u < NPAD; u += 512) dst[u] = src[u];
    }
    for (int u = tid; u < 16 * 48; u += 512) {
        int il = u / 48, c = u - il * 48;
        mskls[c * 16 + il] = mask[(i0 + il) * 48 + c];
    }
    __syncthreads();

    const __bf16* Bbase = hpT + hp_idx(b, hh, 0) + l15 * 32 + qd * 8;
    const float* edrow = edls + hh * NPAD;
    float esv = esT[(b * 4 + hh) * NPAD + i0 + l15];

    f32x4 acc = {0.f, 0.f, 0.f, 0.f};
    float S = 0.f;

    int base = jh * 24;
    int qsh = qd * 8;
    // prime the pipeline (indices clamped; clamped prefetches never consumed)
    bf16x8 Bp0 = *(const bf16x8*)(Bbase + ((base + 0) << 9));
    bf16x8 Bp1 = *(const bf16x8*)(Bbase + ((base + 1) << 9));
    float4 e0p = *(const float4*)&edrow[(base + 0) * 32 + qsh];
    float4 e1p = *(const float4*)&edrow[(base + 0) * 32 + qsh + 4];
    unsigned int mp = mskls[(base + 0) * 16 + l15];

    #pragma unroll 2
    for (int u = 0; u < 24; ++u) {
        int jn1 = base + (u + 1 < 24 ? u + 1 : 23);
        int jn2 = base + (u + 2 < 24 ? u + 2 : 23);
        float4 e0n = *(const float4*)&edrow[jn1 * 32 + qsh];
        float4 e1n = *(const float4*)&edrow[jn1 * 32 + qsh + 4];
        unsigned int mn = mskls[jn1 * 16 + l15];
        bf16x8 Bn = *(const bf16x8*)(Bbase + (jn2 << 9));

        unsigned int mb = (mp >> qsh) & 0xffu;
        float ej[8] = {e0p.x, e0p.y, e0p.z, e0p.w, e1p.x, e1p.y, e1p.z, e1p.w};
        bf16x8 A;
        #pragma unroll
        for (int jj = 0; jj < 8; ++jj) {
            float e = esv + ej[jj];
            e = fmaxf(e, 0.2f * e);
            float p = ((mb >> jj) & 1u) ? exp2f_(e) : 0.f;
            S += p;
            A[jj] = (__bf16)p;
        }
        acc = __builtin_amdgcn_mfma_f32_16x16x32_bf16(A, Bp0, acc, 0, 0, 0);

        Bp0 = Bp1; Bp1 = Bn; e0p = e0n; e1p = e1n; mp = mn;
    }

    S += __shfl_xor(S, 16);
    S += __shfl_xor(S, 32);
    if (qd == 0) Ss[wv][l15] = S;
    if (jh == 1) accs[hh * 64 + lane] = acc;
    __syncthreads();

    if (jh == 0) {
        f32x4 o = accs[hh * 64 + lane];
        #pragma unroll
        for (int r = 0; r < 4; ++r) {
            float st = Ss[hh][qd * 4 + r] + Ss[4 + hh][qd * 4 + r];
            float rs = rcpf(st);
            hbuf[(qd * 4 + r) * 72 + (hh << 4) + l15] =
                fmaxf((acc[r] + o[r]) * rs, 0.f);
        }
    }
    __syncthreads();

    // fused prep1: waves 0..3 (jh==0), mt = hh
    if (jh == 0) {
        int mt = hh;
        bf16x8 Bf0 = ldcvt(&hbuf[l15 * 72 + 8 * qd]);
        bf16x8 Bf1 = ldcvt(&hbuf[l15 * 72 + 32 + 8 * qd]);
        bf16x8 A0 = ldcvt(&gW[(mt * 16 + l15) * 64 + 8 * qd]);
        bf16x8 A1 = ldcvt(&gW[(mt * 16 + l15) * 64 + 32 + 8 * qd]);
        f32x4 a = {0.f, 0.f, 0.f, 0.f};
        a = __builtin_amdgcn_mfma_f32_16x16x32_bf16(A0, Bf0, a, 0, 0, 0);
        a = __builtin_amdgcn_mfma_f32_16x16x32_bf16(A1, Bf1, a, 0, 0, 0);
        float ts = 0.f, td = 0.f;
        #pragma unroll
        for (int r = 0; r < 4; ++r) {
            int dd = mt * 16 + qd * 4 + r;
            ts = fmaf(a[r], avs[dd], ts);
            td = fmaf(a[r], avs[64 + dd], td);
            hp1_t[dd * 24 + l15] = (__bf16)a[r];
        }
        ts += __shfl_xor(ts, 16); ts += __shfl_xor(ts, 32);
        td += __shfl_xor(td, 16); td += __shfl_xor(td, 32);
        if (qd == 0) {
            int n = i0 + l15;
            esT1[(b * 4 + mt) * NPAD + n] = ts;
            edT1[(b * 4 + mt) * NPAD + n] = td;
        }
    }
    __syncthreads();
    if (tid < 256) {
        int dim = tid >> 2, seg = tid & 3;
        int head = dim >> 4, dl = dim & 15;
        int nn0 = i0 + seg * 4;          // i0 multiple of 16 -> same chunk
        int jc = nn0 >> 5, ko = nn0 & 31;
        bf16x4 v = *(bf16x4*)&hp1_t[dim * 24 + seg * 4];
        *(bf16x4*)&hpT1[hp_idx(b, head, jc) + dl * 32 + ko] = v;
    }
}

// ---------------------------------------------------------------------------
// Kernel C: GAT1 aggregation + fused linear head -> d_out.
// Same 8-wave j-split + pipelined loop as kernel B.
// ---------------------------------------------------------------------------
__global__ __launch_bounds__(512, 1) void gat_fin(
    const __bf16* __restrict__ hpT, const float* __restrict__ esT,
    const float* __restrict__ edT, const unsigned int* __restrict__ mask,
    const float* __restrict__ oW, const float* __restrict__ ob,
    float* __restrict__ outp)
{
    __shared__ __align__(16) float edls[4 * NPAD];   // 24 KB
    __shared__ unsigned int mskls[48 * 16];          // 3 KB
    __shared__ float Ss[8][16];
    __shared__ __align__(16) f32x4 accs[256];        // 4 KB
    __shared__ float hbuf[16 * 72];
    __shared__ float oWs[192];
    __shared__ float obs[3];

    int tid  = threadIdx.x;
    int wv   = tid >> 6;
    int lane = tid & 63;
    int l15  = lane & 15;
    int qd   = lane >> 4;
    int hh   = wv & 3;
    int jh   = wv >> 2;
    int b    = blockIdx.x / 94;
    int i0   = (blockIdx.x % 94) * 16;

    if (tid < 192) oWs[tid] = oW[tid];
    if (tid < 3)   obs[tid] = ob[tid];
    {
        const float4* src = (const float4*)(edT + (b * 4) * NPAD);
        float4* dst = (float4*)edls;
        for (int u = tid; u < NPAD; u += 512) dst[u] = src[u];
    }
    for (int u = tid; u < 16 * 48; u += 512) {
        int il = u / 48, c = u - il * 48;
        mskls[c * 16 + il] = mask[(i0 + il) * 48 + c];
    }
    __syncthreads();

    const __bf16* Bbase = hpT + hp_idx(b, hh, 0) + l15 * 32 + qd * 8;
    const float* edrow = edls + hh * NPAD;
    float esv = esT[(b * 4 + hh) * NPAD + i0 + l15];

    f32x4 acc = {0.f, 0.f, 0.f, 0.f};
    float S = 0.f;

    int base = jh * 24;
    int qsh = qd * 8;
    bf16x8 Bp0 = *(const bf16x8*)(Bbase + ((base + 0) << 9));
    bf16x8 Bp1 = *(const bf16x8*)(Bbase + ((base + 1) << 9));
    float4 e0p = *(const float4*)&edrow[(base + 0) * 32 + qsh];
    float4 e1p = *(const float4*)&edrow[(base + 0) * 32 + qsh + 4];
    unsigned int mp = mskls[(base + 0) * 16 + l15];

    #pragma unroll 2
    for (int u = 0; u < 24; ++u) {
        int jn1 = base + (u + 1 < 24 ? u + 1 : 23);
        int jn2 = base + (u + 2 < 24 ? u + 2 : 23);
        float4 e0n = *(const float4*)&edrow[jn1 * 32 + qsh];
        float4 e1n = *(const float4*)&edrow[jn1 * 32 + qsh + 4];
        unsigned int mn = mskls[jn1 * 16 + l15];
        bf16x8 Bn = *(const bf16x8*)(Bbase + (jn2 << 9));

        unsigned int mb = (mp >> qsh) & 0xffu;
        float ej[8] = {e0p.x, e0p.y, e0p.z, e0p.w, e1p.x, e1p.y, e1p.z, e1p.w};
        bf16x8 A;
        #pragma unroll
        for (int jj = 0; jj < 8; ++jj) {
            float e = esv + ej[jj];
            e = fmaxf(e, 0.2f * e);
            float p = ((mb >> jj) & 1u) ? exp2f_(e) : 0.f;
            S += p;
            A[jj] = (__bf16)p;
        }
        acc = __builtin_amdgcn_mfma_f32_16x16x32_bf16(A, Bp0, acc, 0, 0, 0);

        Bp0 = Bp1; Bp1 = Bn; e0p = e0n; e1p = e1n; mp = mn;
    }

    S += __shfl_xor(S, 16);
    S += __shfl_xor(S, 32);
    if (qd == 0) Ss[wv][l15] = S;
    if (jh == 1) accs[hh * 64 + lane] = acc;
    __syncthreads();

    if (jh == 0) {
        f32x4 o = accs[hh * 64 + lane];
        #pragma unroll
        for (int r = 0; r < 4; ++r) {
            float st = Ss[hh][qd * 4 + r] + Ss[4 + hh][qd * 4 + r];
            float rs = rcpf(st);
            hbuf[(qd * 4 + r) * 72 + (hh << 4) + l15] =
                fmaxf((acc[r] + o[r]) * rs, 0.f);
        }
    }
    __syncthreads();

    if (tid < 192) {
        int idx = tid >> 2, ks = tid & 3;
        int nl = idx & 15, o = idx >> 4;
        if (i0 + nl < NNODE) {
            const float* hb = &hbuf[nl * 72 + ks * 16];
            float a = 0.f;
            #pragma unroll
            for (int kk = 0; kk < 16; ++kk)
                a = fmaf(hb[kk], oWs[o * 64 + ks * 16 + kk], a);
            a += __shfl_xor(a, 1);
            a += __shfl_xor(a, 2);
            if (ks == 0)
                outp[(long)b * 3 * NNODE + o * NNODE + i0 + nl] = a + obs[o];
        }
    }
}

// ---------------------------------------------------------------------------
extern "C" void kernel_launch(void* const* d_in, const int* in_sizes, int n_in,
                              void* d_out, int out_size, void* d_ws, size_t ws_size,
                              hipStream_t stream) {
    const float* x    = (const float*)d_in[0];
    const int*   adj  = (const int*)d_in[1];
    const float* Wih0 = (const float*)d_in[2];
    const float* Whh0 = (const float*)d_in[3];
    const float* bih0 = (const float*)d_in[4];
    const float* bhh0 = (const float*)d_in[5];
    const float* Wih1 = (const float*)d_in[6];
    const float* Whh1 = (const float*)d_in[7];
    const float* bih1 = (const float*)d_in[8];
    const float* bhh1 = (const float*)d_in[9];
    const float* g0W  = (const float*)d_in[10];
    const float* g0s  = (const float*)d_in[11];
    const float* g0d  = (const float*)d_in[12];
    const float* g1W  = (const float*)d_in[13];
    const float* g1s  = (const float*)d_in[14];
    const float* g1d  = (const float*)d_in[15];
    const float* oW   = (const float*)d_in[16];
    const float* ob   = (const float*)d_in[17];

    float* ws = (float*)d_ws;
    float*        esT0  = ws;                              // 49152
    float*        edT0  = ws + 49152;                      // 49152
    float*        esT1  = ws + 98304;                      // 49152
    float*        edT1  = ws + 147456;                     // 49152
    __bf16*       hpT0  = (__bf16*)(ws + 196608);          // 786432 bf16
    __bf16*       hpT1  = (__bf16*)(ws + 589824);          // 786432 bf16
    unsigned int* maskp = (unsigned int*)(ws + 983040);    // 72192 u32

    lstm_mask_prep<<<1032, 512, 0, stream>>>(x, Wih0, Whh0, bih0, bhh0,
                                             Wih1, Whh1, bih1, bhh1,
                                             adj, maskp, g0W, g0s, g0d,
                                             hpT0, esT0, edT0);
    gat_mid<<<752, 512, 0, stream>>>(hpT0, esT0, edT0, maskp,
                                     g1W, g1s, g1d, hpT1, esT1, edT1);
    gat_fin<<<752, 512, 0, stream>>>(hpT1, esT1, edT1, maskp,
                                     oW, ob, (float*)d_out);
}